// Round 1
// baseline (721.954 us; speedup 1.0000x reference)
//
#include <hip/hip_runtime.h>

// DiagLinear: out[t][o*16+p] = sum_i x[t][p*256+i] * W[p][o][i] + bias[o*16+p]
// t in [0,16384), o in [0,256), p in [0,16), i in [0,256)
//
// Strategy: bf16 MFMA (16x16x32). Block = 16 tokens x full 4096-wide output.
// - Kernel 1: convert fp32 weights -> bf16 in d_ws (2 MB, stays L2-resident).
// - Kernel 2: stage 16x4096 input rows in LDS as bf16 (row pad +16B for bank
//   spread), each of 16 waves owns one 16-o output strip and accumulates all
//   16 partitions; C-layout (col=lane&15=o, row=(lane>>4)*4+reg=m) lets a lane
//   assemble float4 stores over p-groups -> fully coalesced output writes.

typedef __attribute__((ext_vector_type(4))) float f32x4;
typedef __attribute__((ext_vector_type(8))) short short8;

#define LDS_ROW 8208                 // 4096*2 bytes + 16B pad (16B-aligned, bank-spread)
#define LDS_SIZE (16 * LDS_ROW)      // 131328 B

// round-to-nearest-even fp32 -> bf16, two at a time packed into a uint
__device__ __forceinline__ unsigned int pk2(float a, float b) {
  union { float f; unsigned int u; } x, y;
  x.f = a; y.f = b;
  unsigned int ua = x.u + (0x7fffu + ((x.u >> 16) & 1u));
  unsigned int ub = y.u + (0x7fffu + ((y.u >> 16) & 1u));
  return (ua >> 16) | (ub & 0xffff0000u);
}

__global__ __launch_bounds__(256) void wconv_kernel(
    const float* __restrict__ w, unsigned int* __restrict__ o) {
  int i = blockIdx.x * 256 + threadIdx.x;   // each thread: 4 floats -> 2 uints
  float4 f = ((const float4*)w)[i];
  uint2 u;
  u.x = pk2(f.x, f.y);
  u.y = pk2(f.z, f.w);
  ((uint2*)o)[i] = u;
}

__global__ __launch_bounds__(1024, 1) void diag_gemm_kernel(
    const float* __restrict__ x, const unsigned short* __restrict__ wb,
    const float* __restrict__ bias, float* __restrict__ out) {
  extern __shared__ char lds[];
  const int tid = threadIdx.x;
  const int wv  = tid >> 6;        // wave index 0..15
  const int l   = tid & 63;        // lane
  const long T0 = (long)blockIdx.x * 16;

  // ---- stage A: 16 token rows x 4096 fp32 -> bf16 in LDS (wave wv = row wv) ----
  {
    const float* src = x + (T0 + wv) * 4096;
    char* dst = lds + wv * LDS_ROW;
#pragma unroll
    for (int i = 0; i < 8; ++i) {
      int c = l + 64 * i;                       // 16B chunk index (0..511)
      float4 f0 = ((const float4*)src)[2 * c];
      float4 f1 = ((const float4*)src)[2 * c + 1];
      uint4 u;
      u.x = pk2(f0.x, f0.y);
      u.y = pk2(f0.z, f0.w);
      u.z = pk2(f1.x, f1.y);
      u.w = pk2(f1.z, f1.w);
      *(uint4*)(dst + c * 16) = u;
    }
  }
  __syncthreads();

  // ---- compute: wave wv owns o-strip [o0, o0+16) across all 16 partitions ----
  const int n  = l & 15;     // MFMA col (o_local) / A row (token m for A-frag)
  const int kg = l >> 4;     // k-group (k = kg*8 + j within a 32-chunk)
  const int o0 = wv * 16;

  const char* abase = lds + n * LDS_ROW + kg * 16;               // A[m=n][k=kg*8+j]
  const unsigned short* bbase = wb + (o0 + n) * 256 + kg * 8;    // B[k][n]=W[p][o0+n][k]
  float* obase = out + T0 * 4096 + (long)(o0 + n) * 16;
  const float* bptr = bias + (o0 + n) * 16;

#pragma unroll
  for (int pg = 0; pg < 4; ++pg) {
    f32x4 acc[4];
#pragma unroll
    for (int pi = 0; pi < 4; ++pi) acc[pi] = (f32x4){0.f, 0.f, 0.f, 0.f};

#pragma unroll
    for (int pi = 0; pi < 4; ++pi) {
      const int p = pg * 4 + pi;
      const char* ap = abase + p * 512;                 // p*256 bf16 = 512 B
      const unsigned short* bp = bbase + p * 65536;     // p*256*256 elems
      short8 a[8], b[8];
#pragma unroll
      for (int ks = 0; ks < 8; ++ks) {
        a[ks] = *(const short8*)(ap + ks * 64);         // ds_read_b128
        b[ks] = *(const short8*)(bp + ks * 32);         // global dwordx4 (L2-hot)
      }
#pragma unroll
      for (int ks = 0; ks < 8; ++ks)
        acc[pi] = __builtin_amdgcn_mfma_f32_16x16x32_bf16(a[ks], b[ks], acc[pi], 0, 0, 0);
    }

    // flush p-group: lane holds out[m][ (o0+n)*16 + pg*4 .. +3 ] across acc[0..3]
    float4 bv = *(const float4*)(bptr + pg * 4);
#pragma unroll
    for (int r = 0; r < 4; ++r) {
      int m = kg * 4 + r;   // C row = (lane>>4)*4 + reg
      float4 v = make_float4(acc[0][r] + bv.x, acc[1][r] + bv.y,
                             acc[2][r] + bv.z, acc[3][r] + bv.w);
      *(float4*)(obase + (long)m * 4096 + pg * 4) = v;
    }
  }
}

extern "C" void kernel_launch(void* const* d_in, const int* in_sizes, int n_in,
                              void* d_out, int out_size, void* d_ws, size_t ws_size,
                              hipStream_t stream) {
  const float* x    = (const float*)d_in[0];   // (8,2048,4096) fp32
  const float* w    = (const float*)d_in[1];   // (16,256,256) fp32
  const float* bias = (const float*)d_in[2];   // (4096,) fp32
  float* out = (float*)d_out;
  unsigned int* wb = (unsigned int*)d_ws;      // 2 MB bf16 weights

  // allow 128.25 KB dynamic LDS (idempotent; set on first (uncaptured) call)
  (void)hipFuncSetAttribute((const void*)diag_gemm_kernel,
                            hipFuncAttributeMaxDynamicSharedMemorySize, LDS_SIZE);

  // 1,048,576 weight elems / 4 per thread / 256 threads = 1024 blocks
  wconv_kernel<<<1024, 256, 0, stream>>>(w, wb);

  // 16384 tokens / 16 per block = 1024 blocks
  diag_gemm_kernel<<<1024, 1024, LDS_SIZE, stream>>>(
      x, (const unsigned short*)wb, bias, out);
}

// Round 2
// 673.534 us; speedup vs baseline: 1.0719x; 1.0719x over previous
//
#include <hip/hip_runtime.h>

// DiagLinear: out[t][o*16+p] = sum_i x[t][p*256+i] * W[p][o][i] + bias[o*16+p]
// t in [0,16384), o in [0,256), p in [0,16), i in [0,256)
//
// R2: 512-thread blocks (8 waves -> 256-VGPR budget vs 128 at 1024 threads),
// all-16-p result registers flushed as contiguous 64B/lane (kills the 2.2x
// write amplification seen in R1), explicit ping-pong prefetch of B (global)
// and A (LDS) fragments chained across the two o-strips each wave owns.

typedef __attribute__((ext_vector_type(4))) float f32x4;
typedef __attribute__((ext_vector_type(8))) short short8;

#define LDS_ROW 8208                 // 4096*2 bytes + 16B pad
#define LDS_SIZE (16 * LDS_ROW)      // 131328 B -> 1 block/CU

// round-to-nearest-even fp32 -> bf16, packed pair
__device__ __forceinline__ unsigned int pk2(float a, float b) {
  union { float f; unsigned int u; } x, y;
  x.f = a; y.f = b;
  unsigned int ua = x.u + (0x7fffu + ((x.u >> 16) & 1u));
  unsigned int ub = y.u + (0x7fffu + ((y.u >> 16) & 1u));
  return (ua >> 16) | (ub & 0xffff0000u);
}

__global__ __launch_bounds__(256) void wconv_kernel(
    const float* __restrict__ w, unsigned int* __restrict__ o) {
  int i = blockIdx.x * 256 + threadIdx.x;   // 4 floats -> 2 uints per thread
  float4 f = ((const float4*)w)[i];
  uint2 u;
  u.x = pk2(f.x, f.y);
  u.y = pk2(f.z, f.w);
  ((uint2*)o)[i] = u;
}

__global__ __launch_bounds__(512, 2) void diag_gemm_kernel(
    const float* __restrict__ x, const unsigned short* __restrict__ wb,
    const float* __restrict__ bias, float* __restrict__ out) {
  extern __shared__ char lds[];
  const int tid = threadIdx.x;
  const int wv  = tid >> 6;        // wave 0..7
  const int l   = tid & 63;
  const long T0 = (long)blockIdx.x * 16;

  const int n  = l & 15;           // MFMA col (o_local) / A token row
  const int kg = l >> 4;           // k-group

  // strip s covers o0 = (wv + 8*s)*16
  const unsigned short* bbs0 = wb + (wv * 16 + n) * 256 + kg * 8;
  const unsigned short* bbs1 = wb + ((wv + 8) * 16 + n) * 256 + kg * 8;

  short8 a[2][8], b[2][8];

  // prefetch B for (strip0, p0) before staging even begins
#pragma unroll
  for (int ks = 0; ks < 8; ++ks) b[0][ks] = *(const short8*)(bbs0 + ks * 32);

  // ---- stage 16 token rows (fp32 -> bf16) into LDS; wave handles 2 rows ----
#pragma unroll
  for (int rr = 0; rr < 2; ++rr) {
    const int row = wv * 2 + rr;
    const float* src = x + (T0 + row) * 4096;
    char* dst = lds + row * LDS_ROW;
#pragma unroll
    for (int i = 0; i < 8; ++i) {
      int c = l + 64 * i;                       // 16B chunk index 0..511
      float4 f0 = ((const float4*)src)[2 * c];
      float4 f1 = ((const float4*)src)[2 * c + 1];
      uint4 u;
      u.x = pk2(f0.x, f0.y);
      u.y = pk2(f0.z, f0.w);
      u.z = pk2(f1.x, f1.y);
      u.w = pk2(f1.z, f1.w);
      *(uint4*)(dst + c * 16) = u;
    }
  }
  __syncthreads();

  const char* abase = lds + n * LDS_ROW + kg * 16;
  // preload A for p=0
#pragma unroll
  for (int ks = 0; ks < 8; ++ks) a[0][ks] = *(const short8*)(abase + ks * 64);

  float* obase = out + T0 * 4096;

#pragma unroll
  for (int s = 0; s < 2; ++s) {
    const int o0 = (wv + 8 * s) * 16;
    f32x4 res[16];

#pragma unroll
    for (int p = 0; p < 16; ++p) {
      const int g = s * 16 + p;                 // global iteration 0..31
      const int cur = g & 1, nxt = cur ^ 1;
      if (g < 31) {
        const int gn = g + 1;
        const unsigned short* bp =
            ((gn & 16) ? bbs1 : bbs0) + (gn & 15) * 65536;
#pragma unroll
        for (int ks = 0; ks < 8; ++ks)
          b[nxt][ks] = *(const short8*)(bp + ks * 32);      // global, L2-hot
        const char* ap = abase + (gn & 15) * 512;
#pragma unroll
        for (int ks = 0; ks < 8; ++ks)
          a[nxt][ks] = *(const short8*)(ap + ks * 64);      // ds_read_b128
      }
      f32x4 acc = (f32x4){0.f, 0.f, 0.f, 0.f};
#pragma unroll
      for (int ks = 0; ks < 8; ++ks)
        acc = __builtin_amdgcn_mfma_f32_16x16x32_bf16(a[cur][ks], b[cur][ks],
                                                      acc, 0, 0, 0);
      res[p] = acc;
    }

    // ---- epilogue: lane owns 64B contiguous per row -> 4 back-to-back
    //      dwordx4 fully cover every sector (no RMW) ----
    const float* bp2 = bias + (o0 + n) * 16;
    float4 bv0 = ((const float4*)bp2)[0];
    float4 bv1 = ((const float4*)bp2)[1];
    float4 bv2 = ((const float4*)bp2)[2];
    float4 bv3 = ((const float4*)bp2)[3];
    float* ob = obase + (long)(o0 + n) * 16;
#pragma unroll
    for (int r = 0; r < 4; ++r) {
      float* orow = ob + (long)(kg * 4 + r) * 4096;
      float4 v0 = make_float4(res[0][r] + bv0.x, res[1][r] + bv0.y,
                              res[2][r] + bv0.z, res[3][r] + bv0.w);
      float4 v1 = make_float4(res[4][r] + bv1.x, res[5][r] + bv1.y,
                              res[6][r] + bv1.z, res[7][r] + bv1.w);
      float4 v2 = make_float4(res[8][r] + bv2.x, res[9][r] + bv2.y,
                              res[10][r] + bv2.z, res[11][r] + bv2.w);
      float4 v3 = make_float4(res[12][r] + bv3.x, res[13][r] + bv3.y,
                              res[14][r] + bv3.z, res[15][r] + bv3.w);
      ((float4*)orow)[0] = v0;
      ((float4*)orow)[1] = v1;
      ((float4*)orow)[2] = v2;
      ((float4*)orow)[3] = v3;
    }
  }
}

extern "C" void kernel_launch(void* const* d_in, const int* in_sizes, int n_in,
                              void* d_out, int out_size, void* d_ws, size_t ws_size,
                              hipStream_t stream) {
  const float* x    = (const float*)d_in[0];   // (8,2048,4096) fp32
  const float* w    = (const float*)d_in[1];   // (16,256,256) fp32
  const float* bias = (const float*)d_in[2];   // (4096,) fp32
  float* out = (float*)d_out;
  unsigned int* wb = (unsigned int*)d_ws;      // 2 MB bf16 weights

  (void)hipFuncSetAttribute((const void*)diag_gemm_kernel,
                            hipFuncAttributeMaxDynamicSharedMemorySize, LDS_SIZE);

  wconv_kernel<<<1024, 256, 0, stream>>>(w, wb);

  diag_gemm_kernel<<<1024, 512, LDS_SIZE, stream>>>(
      x, (const unsigned short*)wb, bias, out);
}